// Round 4
// baseline (217.931 us; speedup 1.0000x reference)
//
#include <hip/hip_runtime.h>
#include <math.h>

#define Hd 256
#define Wd 256
#define Cd 128
#define BIGV 1.0e9f

static __device__ __forceinline__ float softplus_f(float x) {
    return fmaxf(x, 0.0f) + log1pf(expf(-fabsf(x)));
}

// ---- DPP helpers (gfx9/CDNA DPP controls; old = FLT_MAX = min identity) ----
#define FMAXBITS 0x7F7FFFFF
template<int CTRL, int RM>
static __device__ __forceinline__ float dpp_mv(float x) {
    return __int_as_float(__builtin_amdgcn_update_dpp(
        FMAXBITS, __float_as_int(x), CTRL, RM, 0xF, false));
}
template<int CTRL, int RM>
static __device__ __forceinline__ float dpp_min(float x) {
    return fminf(x, dpp_mv<CTRL, RM>(x));
}
// inclusive prefix-min across 64 lanes
static __device__ __forceinline__ float wave_prefmin(float x) {
    x = dpp_min<0x111, 0xF>(x);   // row_shr:1
    x = dpp_min<0x112, 0xF>(x);   // row_shr:2
    x = dpp_min<0x114, 0xF>(x);   // row_shr:4
    x = dpp_min<0x118, 0xF>(x);   // row_shr:8
    x = dpp_min<0x142, 0xA>(x);   // row_bcast15 -> rows 1,3
    x = dpp_min<0x143, 0xC>(x);   // row_bcast31 -> rows 2,3
    return x;
}

#define TILE 16
#define HPX 18
#define PXN 324
#define SP  325
#define CHUNK 32

// ---------------------------------------------------------------------------
// Kernel 1: COST-ONLY per-pixel work (proven R12 version, unchanged).
// ---------------------------------------------------------------------------
__global__ __launch_bounds__(256) void k_cost(
    const float* __restrict__ feat,
    float* __restrict__ out, float* __restrict__ costP)
{
    __shared__ float stage[CHUNK * SP];
    __shared__ float normL[PXN];

    const int t  = threadIdx.x;
    const int r0 = blockIdx.y * TILE;
    const int c0 = blockIdx.x * TILE;

    const int lr = t >> 4, lc = t & 15;
    const int r = r0 + lr, c = c0 + lc;
    const int px0 = (lr + 1) * HPX + (lc + 1);

    float dotv[8];
#pragma unroll
    for (int j = 0; j < 8; ++j) dotv[j] = 0.0f;

    for (int ch0 = 0; ch0 < Cd; ch0 += CHUNK) {
        __syncthreads();
        for (int i = t; i < PXN * 8; i += 256) {
            int px = i >> 3, f4 = i & 7;
            int pr = px / HPX;
            int pc = px - pr * HPX;
            int gr = r0 - 1 + pr, gc = c0 - 1 + pc;
            float4 v = make_float4(0.f, 0.f, 0.f, 0.f);
            if ((unsigned)gr < Hd && (unsigned)gc < Wd) {
                v = *reinterpret_cast<const float4*>(
                        &feat[(((gr << 8) + gc) * Cd) + ch0 + (f4 << 2)]);
            }
            int chb = f4 << 2;
            stage[(chb + 0) * SP + px] = v.x;
            stage[(chb + 1) * SP + px] = v.y;
            stage[(chb + 2) * SP + px] = v.z;
            stage[(chb + 3) * SP + px] = v.w;
        }
        __syncthreads();
        for (int px = t; px < PXN; px += 256) {
            float s = 0.0f;
#pragma unroll
            for (int ch = 0; ch < CHUNK; ++ch) {
                float v = stage[ch * SP + px];
                s = fmaf(v, v, s);
            }
            if (ch0 == 0) normL[px] = s; else normL[px] += s;
        }
        for (int ch = 0; ch < CHUNK; ++ch) {
            const float* pl = stage + ch * SP + px0;
            float x  = pl[0];
            float n0 = pl[-HPX - 1], n1 = pl[-HPX], n2 = pl[-HPX + 1];
            float n3 = pl[-1],                      n4 = pl[1];
            float n5 = pl[HPX - 1],  n6 = pl[HPX],  n7 = pl[HPX + 1];

            dotv[0] = fmaf(x, n0, dotv[0]);
            dotv[1] = fmaf(x, n1, dotv[1]);
            dotv[2] = fmaf(x, n2, dotv[2]);
            dotv[3] = fmaf(x, n3, dotv[3]);
            dotv[4] = fmaf(x, n4, dotv[4]);
            dotv[5] = fmaf(x, n5, dotv[5]);
            dotv[6] = fmaf(x, n6, dotv[6]);
            dotv[7] = fmaf(x, n7, dotv[7]);
        }
    }
    __syncthreads();

    const int p = (r << 8) + c;
    float np = fmaxf(sqrtf(normL[px0]), 1e-12f);
    const int drr[8] = {-1,-1,-1, 0, 0, 1, 1, 1};
    const int dcc[8] = {-1, 0, 1,-1, 1,-1, 0, 1};
    const int nof[8] = {-HPX-1,-HPX,-HPX+1,-1,1,HPX-1,HPX,HPX+1};
#pragma unroll
    for (int j = 0; j < 8; ++j) {
        int nr = r + drr[j], nc = c + dcc[j];
        float cj;
        if ((unsigned)nr < Hd && (unsigned)nc < Wd) {
            float nn = fmaxf(sqrtf(normL[px0 + nof[j]]), 1e-12f);
            cj = 1.0f - dotv[j] / (np * nn);
        } else {
            cj = BIGV;
        }
        costP[(j << 16) + p] = cj;
        out[p * 10 + 1 + j]  = cj;
    }
}

// ---------------------------------------------------------------------------
// Kernel 2: per-row exclusive prefix sums of horizontal edge costs (unchanged).
// ---------------------------------------------------------------------------
__global__ __launch_bounds__(64) void k_scan(
    const float* __restrict__ costP, float* __restrict__ PR, float* __restrict__ PRm)
{
    const int r = blockIdx.x;
    const int l = threadIdx.x;
    const int base = (r << 8) + (l << 2);

    {
        const float4 c4 = *(const float4*)&costP[(4 << 16) + base];
        float a0 = c4.x, a1 = a0 + c4.y, a2 = a1 + c4.z, a3 = a2 + c4.w;
        float ta = a3;
#pragma unroll
        for (int o = 1; o < 64; o <<= 1) {
            float xa = __shfl_up(ta, o, 64);
            if (l >= o) ta += xa;
        }
        float ea = __shfl_up(ta, 1, 64); if (l == 0) ea = 0.0f;
        float4 P; P.x = ea; P.y = ea + a0; P.z = ea + a1; P.w = ea + a2;
        *(float4*)&PR[base] = P;
    }
    {
        const float4 m = *(const float4*)&costP[(3 << 16) + (r << 8) + (252 - (l << 2))];
        float w0 = m.w, w1_ = m.z, w2_ = m.y, w3 = m.x;
        float a0 = w0, a1 = a0 + w1_, a2 = a1 + w2_, a3 = a2 + w3;
        float ta = a3;
#pragma unroll
        for (int o = 1; o < 64; o <<= 1) {
            float xa = __shfl_up(ta, o, 64);
            if (l >= o) ta += xa;
        }
        float ea = __shfl_up(ta, 1, 64); if (l == 0) ea = 0.0f;
        float4 P; P.x = ea; P.y = ea + a0; P.z = ea + a1; P.w = ea + a2;
        *(float4*)&PRm[base] = P;
    }
}

// ---------------------------------------------------------------------------
// Kernel 3 (R15): R13/R14 paired-sweep structure + ONE change: a
// __builtin_amdgcn_sched_barrier(0) pinning each row-step's refill loads.
// R14 post-mortem: even with launch_bounds(256,1), VGPR stayed 88 -> the GCN
// scheduler SINKS the prefetch loads to their uses (pressure heuristic),
// collapsing the pipeline and exposing ~600 cyc of L2/L3 latency per row
// (true of the original k_sweep too: PIPE=8 buffers=128 regs but it compiled
// to 124 total). The barrier forbids code motion across the iteration end,
// forcing loads to issue PIPE=4 rows (>1000 cyc) ahead and forcing the
// allocator to materialize the buffers; the compiler's automatic counted
// s_waitcnt vmcnt(N) then gives the AITER-style never-drain pipeline.
// ---------------------------------------------------------------------------
#define PIPE 4

static __device__ __forceinline__ float4 ld4m(const float* p, int r, int l, int M) {
    if (!M) return *(const float4*)&p[(r << 8) + (l << 2)];
    float4 v = *(const float4*)&p[(r << 8) + (252 - (l << 2))];
    return make_float4(v.w, v.z, v.y, v.x);
}

__global__ __launch_bounds__(256, 1) void k_main(
    const float* __restrict__ feat,
    const float* __restrict__ w1, const float* __restrict__ b1,
    const float* __restrict__ w2, const float* __restrict__ b2,
    const float* __restrict__ dlt, const float* __restrict__ gmm,
    const float* __restrict__ bta, const int* __restrict__ endn,
    const float* __restrict__ costP, const float* __restrict__ PR,
    const float* __restrict__ PRm, const int* __restrict__ startn,
    float* __restrict__ out, float* __restrict__ distQ)
{
    if (blockIdx.x < 2) {
        // ============ PAIRED SWEEP PATH: sweep A (M=0) + sweep B (M=1) =====
        const int l = threadIdx.x;
        if (l >= 64) return;
        __builtin_amdgcn_s_setprio(1);     // bias CU arbitration to the DP chain
        const int pair  = blockIdx.x;      // 0: {sw0,sw1} down; 1: {sw2,sw3} up
        const int vdown = (pair == 0);
        const int sr  = startn[0];
        const int scA = startn[1];
        const int scB = 255 - startn[1];
        const float* __restrict__ PRa = PR;
        const float* __restrict__ PRb = PRm;
        const int pIncA = vdown ? 7 : 2, pDecA = vdown ? 5 : 0;
        const int pIncB = vdown ? 5 : 0, pDecB = vdown ? 7 : 2;
        const int pStr  = vdown ? 6 : 1;
        const float* __restrict__ cInA = costP + (pIncA << 16);
        const float* __restrict__ cStA = costP + (pStr  << 16);
        const float* __restrict__ cDeA = costP + (pDecA << 16);
        const float* __restrict__ cInB = costP + (pIncB << 16);
        const float* __restrict__ cStB = cStA;   // same plane, read mirrored
        const float* __restrict__ cDeB = costP + (pDecB << 16);
        float* __restrict__ OA = distQ + ((pair ? 2 : 0) << 16);
        float* __restrict__ OB = distQ + ((pair ? 3 : 1) << 16);
        const int iStart = vdown ? sr : (255 - sr);

        const float4 BIG4 = make_float4(BIGV, BIGV, BIGV, BIGV);

        float4 svA = BIG4, svB = BIG4;
        {
            int ka = scA - (l << 2);
            if (ka == 0) svA.x = 0.0f;
            if (ka == 1) svA.y = 0.0f;
            if (ka == 2) svA.z = 0.0f;
            if (ka == 3) svA.w = 0.0f;
            int kb = scB - (l << 2);
            if (kb == 0) svB.x = 0.0f;
            if (kb == 1) svB.y = 0.0f;
            if (kb == 2) svB.z = 0.0f;
            if (kb == 3) svB.w = 0.0f;
        }

#define ROW_OF(ii)  (vdown ? ((ii) > 255 ? 255 : (ii)) : (255 - ((ii) > 255 ? 255 : (ii))))
#define ROWP_OF(ii) (vdown ? (((ii) - 1) < 0 ? 0 : (((ii) - 1) > 255 ? 255 : ((ii) - 1))) \
                           : (255 - (((ii) - 1) < 0 ? 0 : (((ii) - 1) > 255 ? 255 : ((ii) - 1)))))

        float4 aPR[PIPE], aI[PIPE], aS[PIPE], aD[PIPE];
        float4 bPR[PIPE], bI[PIPE], bS[PIPE], bD[PIPE];
#pragma unroll
        for (int k = 0; k < PIPE; ++k) {
            int rP = ROW_OF(k), rC = ROWP_OF(k);
            aPR[k] = *(const float4*)&PRa[(rP << 8) + (l << 2)];
            aI[k]  = ld4m(cInA, rC, l, 0);
            aS[k]  = ld4m(cStA, rC, l, 0);
            aD[k]  = ld4m(cDeA, rC, l, 0);
            bPR[k] = *(const float4*)&PRb[(rP << 8) + (l << 2)];
            bI[k]  = ld4m(cInB, rC, l, 1);
            bS[k]  = ld4m(cStB, rC, l, 1);
            bD[k]  = ld4m(cDeB, rC, l, 1);
        }
        __builtin_amdgcn_sched_barrier(0);  // pin prologue loads before loop

        float4 DpA = BIG4, DpB = BIG4;
        for (int ib = 0; ib < 256; ib += PIPE) {
#pragma unroll
            for (int k = 0; k < PIPE; ++k) {
                const int i = ib + k;
                const int r = vdown ? i : 255 - i;

                // ---- chain A ----
                float4 PA = aPR[k], AI = aI[k], AS = aS[k], AD = aD[k];
                float aS0 = DpA.x + AS.x, aS1 = DpA.y + AS.y,
                      aS2 = DpA.z + AS.z, aS3 = DpA.w + AS.w;
                float aI0 = DpA.x + AI.x, aI1 = DpA.y + AI.y,
                      aI2 = DpA.z + AI.z, aI3 = DpA.w + AI.w;
                float aD0 = DpA.x + AD.x, aD1 = DpA.y + AD.y,
                      aD2 = DpA.z + AD.z, aD3 = DpA.w + AD.w;
                float aIm = dpp_mv<0x138, 0xF>(aI3);   // wave_shr1
                float aDn = dpp_mv<0x130, 0xF>(aD0);   // wave_shl1
                float4 cA;
                cA.x = fminf(aS0, fminf(aIm, aD1));
                cA.y = fminf(aS1, fminf(aI0, aD2));
                cA.z = fminf(aS2, fminf(aI1, aD3));
                cA.w = fminf(aS3, fminf(aI2, aDn));

                // ---- chain B ----
                float4 PB = bPR[k], BI = bI[k], BS = bS[k], BD = bD[k];
                float bS0 = DpB.x + BS.x, bS1 = DpB.y + BS.y,
                      bS2 = DpB.z + BS.z, bS3 = DpB.w + BS.w;
                float bI0 = DpB.x + BI.x, bI1 = DpB.y + BI.y,
                      bI2 = DpB.z + BI.z, bI3 = DpB.w + BI.w;
                float bD0 = DpB.x + BD.x, bD1 = DpB.y + BD.y,
                      bD2 = DpB.z + BD.z, bD3 = DpB.w + BD.w;
                float bIm = dpp_mv<0x138, 0xF>(bI3);
                float bDn = dpp_mv<0x130, 0xF>(bD0);
                float4 cB;
                cB.x = fminf(bS0, fminf(bIm, bD1));
                cB.y = fminf(bS1, fminf(bI0, bD2));
                cB.z = fminf(bS2, fminf(bI1, bD3));
                cB.w = fminf(bS3, fminf(bI2, bDn));

                if (i == iStart) {                     // shared uniform branch
                    cA.x = fminf(cA.x, svA.x); cA.y = fminf(cA.y, svA.y);
                    cA.z = fminf(cA.z, svA.z); cA.w = fminf(cA.w, svA.w);
                    cB.x = fminf(cB.x, svB.x); cB.y = fminf(cB.y, svB.y);
                    cB.z = fminf(cB.z, svB.z); cB.w = fminf(cB.w, svB.w);
                }

                // ---- closures (independent; compiler interleaves) ----
                float za0 = cA.x - PA.x;
                float za1 = fminf(cA.y - PA.y, za0);
                float za2 = fminf(cA.z - PA.z, za1);
                float za3 = fminf(cA.w - PA.w, za2);
                float zb0 = cB.x - PB.x;
                float zb1 = fminf(cB.y - PB.y, zb0);
                float zb2 = fminf(cB.z - PB.z, zb1);
                float zb3 = fminf(cB.w - PB.w, zb2);
                float wa  = wave_prefmin(za3);
                float wb  = wave_prefmin(zb3);
                float ea  = dpp_mv<0x138, 0xF>(wa);
                float eb  = dpp_mv<0x138, 0xF>(wb);
                float4 DA, DB;
                DA.x = PA.x + fminf(za0, ea);
                DA.y = PA.y + fminf(za1, ea);
                DA.z = PA.z + fminf(za2, ea);
                DA.w = PA.w + fminf(za3, ea);
                DB.x = PB.x + fminf(zb0, eb);
                DB.y = PB.y + fminf(zb1, eb);
                DB.z = PB.z + fminf(zb2, eb);
                DB.w = PB.w + fminf(zb3, eb);

                *(float4*)&OA[(r << 8) + (l << 2)] = DA;
                *(float4*)&OB[(r << 8) + (l << 2)] = DB;
                DpA = DA; DpB = DB;

                // refill slot k with iteration i+PIPE operands
                {
                    const int jn = i + PIPE;
                    int rP = ROW_OF(jn), rC = ROWP_OF(jn);
                    aPR[k] = *(const float4*)&PRa[(rP << 8) + (l << 2)];
                    aI[k]  = ld4m(cInA, rC, l, 0);
                    aS[k]  = ld4m(cStA, rC, l, 0);
                    aD[k]  = ld4m(cDeA, rC, l, 0);
                    bPR[k] = *(const float4*)&PRb[(rP << 8) + (l << 2)];
                    bI[k]  = ld4m(cInB, rC, l, 1);
                    bS[k]  = ld4m(cStB, rC, l, 1);
                    bD[k]  = ld4m(cDeB, rC, l, 1);
                }
                // R15: forbid the scheduler from sinking the refill loads out
                // of this iteration (the pipeline-collapse seen in R0..R14).
                __builtin_amdgcn_sched_barrier(0);
            }
        }
#undef ROW_OF
#undef ROWP_OF
        return;
    }

    // ================= HEURISTIC PATH (unchanged) ==========================
    __shared__ float  stage[CHUNK * SP];
    __shared__ float4 w1L[Cd * 8];
    __shared__ float  endfL[64];
    __shared__ float  vendL[64];
    __shared__ float  vendS;

    const int t  = threadIdx.x;
    const int b  = blockIdx.x - 2;
    const int r0 = (b >> 4) * TILE;
    const int c0 = (b & 15) * TILE;

    for (int i = t; i < Cd * 8; i += 256) w1L[i] = ((const float4*)w1)[i];
    const int er = endn[0], ec = endn[1];
    if (t < 64) {
        endfL[t] = feat[(er * Wd + ec) * Cd + t];
        float s1 = 0.0f, s2 = 0.0f;
#pragma unroll
        for (int dr = -1; dr <= 1; ++dr)
#pragma unroll
            for (int dc = -1; dc <= 1; ++dc) {
                int gr = er + dr, gc = ec + dc;
                if ((unsigned)gr < Hd && (unsigned)gc < Wd) {
                    float x = feat[((gr << 8) + gc) * Cd + 64 + t];
                    s1 += x; s2 = fmaf(x, x, s2);
                }
            }
        float m = s1 * (1.0f / 9.0f);
        vendL[t] = s2 * (1.0f / 9.0f) - m * m;
    }

    const int lr = t >> 4, lc = t & 15;
    const int r = r0 + lr, c = c0 + lc;
    const int px0 = (lr + 1) * HPX + (lc + 1);

    float4 hv[8];
#pragma unroll
    for (int j = 0; j < 8; ++j) hv[j] = make_float4(0.f, 0.f, 0.f, 0.f);
    float gm_acc = 0.0f, var_acc = 0.0f, abs_acc = 0.0f;

    for (int ch0 = 0; ch0 < Cd; ch0 += CHUNK) {
        __syncthreads();
        for (int i = t; i < PXN * 8; i += 256) {
            int px = i >> 3, f4 = i & 7;
            int pr = px / HPX;
            int pc = px - pr * HPX;
            int gr = r0 - 1 + pr, gc = c0 - 1 + pc;
            float4 v = make_float4(0.f, 0.f, 0.f, 0.f);
            if ((unsigned)gr < Hd && (unsigned)gc < Wd) {
                v = *reinterpret_cast<const float4*>(
                        &feat[(((gr << 8) + gc) * Cd) + ch0 + (f4 << 2)]);
            }
            int chb = f4 << 2;
            stage[(chb + 0) * SP + px] = v.x;
            stage[(chb + 1) * SP + px] = v.y;
            stage[(chb + 2) * SP + px] = v.z;
            stage[(chb + 3) * SP + px] = v.w;
        }
        __syncthreads();
        const bool is_hf = (ch0 >= 64);
        for (int ch = 0; ch < CHUNK; ++ch) {
            const float* pl = stage + ch * SP + px0;
            float x  = pl[0];
            float n0 = pl[-HPX - 1], n1 = pl[-HPX], n2 = pl[-HPX + 1];
            float n3 = pl[-1],                      n4 = pl[1];
            float n5 = pl[HPX - 1],  n6 = pl[HPX],  n7 = pl[HPX + 1];

            float gx = (n2 + 2.f * n4 + n7) - (n0 + 2.f * n3 + n5);
            float gy = (n5 + 2.f * n6 + n7) - (n0 + 2.f * n1 + n2);
            gm_acc += sqrtf(gx * gx + gy * gy);

            if (is_hf) {
                float s1 = x + n0 + n1 + n2 + n3 + n4 + n5 + n6 + n7;
                float s2 = x*x + n0*n0 + n1*n1 + n2*n2 + n3*n3 + n4*n4
                         + n5*n5 + n6*n6 + n7*n7;
                float m = s1 * (1.0f / 9.0f);
                var_acc += s2 * (1.0f / 9.0f) - m * m;
            } else {
                float dlf = x - endfL[ch0 + ch];
                abs_acc = fmaf(dlf, dlf, abs_acc);
            }

            const float4* __restrict__ wr4 = &w1L[(ch0 + ch) << 3];
#pragma unroll
            for (int j4 = 0; j4 < 8; ++j4) {
                float4 wv = wr4[j4];
                hv[j4].x = fmaf(x, wv.x, hv[j4].x);
                hv[j4].y = fmaf(x, wv.y, hv[j4].y);
                hv[j4].z = fmaf(x, wv.z, hv[j4].z);
                hv[j4].w = fmaf(x, wv.w, hv[j4].w);
            }
        }
    }
    __syncthreads();

    if (t < 64) {
        float v = vendL[t];
#pragma unroll
        for (int o = 32; o > 0; o >>= 1) v += __shfl_down(v, o, 64);
        if (t == 0) vendS = v;
    }
    __syncthreads();
    const float vend = vendS;

    const int p = (r << 8) + c;
    float geo  = gm_acc * (1.0f / 128.0f);
    float absp = sqrtf(abs_acc);
    float o = b2[0];
#pragma unroll
    for (int j4 = 0; j4 < 8; ++j4) {
#pragma unroll
        for (int cc = 0; cc < 4; ++cc) {
            int j = (j4 << 2) + cc;
            float hj = fmaxf(((const float*)&hv[j4])[cc] + b1[j], 0.0f);
            o = fmaf(hj, w2[j], o);
        }
    }
    float omg = 1.0f / (1.0f + expf(-o));
    float dS = softplus_f(dlt[0]);
    float gS = softplus_f(gmm[0]);
    float bS = softplus_f(bta[0]);
    float heur = dS * geo + omg * gS * (vend - var_acc)
               + (1.0f - omg) * bS * absp;
    out[p * 10] = fmaxf(heur, 0.0f);
}

// ---------------------------------------------------------------------------
// Kernel 4: merge the 4 quadrant planes (un-mirroring planes 1,3) -> out ch 9
// ---------------------------------------------------------------------------
__global__ __launch_bounds__(256) void k_merge(
    const float* __restrict__ distQ, float* __restrict__ out)
{
    int p  = blockIdx.x * 256 + threadIdx.x;
    int pm = (p & ~255) + (255 - (p & 255));
    float v = fminf(fminf(distQ[p],           distQ[(2 << 16) + p]),
                    fminf(distQ[(1 << 16) + pm], distQ[(3 << 16) + pm]));
    out[p * 10 + 9] = fminf(v, BIGV);
}

// ---------------------------------------------------------------------------
extern "C" void kernel_launch(void* const* d_in, const int* in_sizes, int n_in,
                              void* d_out, int out_size, void* d_ws, size_t ws_size,
                              hipStream_t stream)
{
    const float* feat  = (const float*)d_in[0];
    const float* dlt   = (const float*)d_in[1];
    const float* gmm   = (const float*)d_in[2];
    const float* bta   = (const float*)d_in[3];
    const float* w1    = (const float*)d_in[4];
    const float* b1    = (const float*)d_in[5];
    const float* w2    = (const float*)d_in[6];
    const float* b2    = (const float*)d_in[7];
    const int*   startn= (const int*)d_in[8];
    const int*   endn  = (const int*)d_in[9];
    float* out = (float*)d_out;
    float* ws  = (float*)d_ws;

    float* costP = ws;                   // 8 planes
    float* PR    = ws + 8  * 65536;
    float* PRm   = ws + 9  * 65536;
    float* distQ = ws + 10 * 65536;      // 4 quadrant planes

    dim3 g16(16, 16);
    k_cost<<<g16, 256, 0, stream>>>(feat, out, costP);
    k_scan<<<256, 64, 0, stream>>>(costP, PR, PRm);
    k_main<<<258, 256, 0, stream>>>(feat, w1, b1, w2, b2, dlt, gmm, bta, endn,
                                    costP, PR, PRm, startn, out, distQ);
    k_merge<<<256, 256, 0, stream>>>(distQ, out);
}

// Round 5
// 174.259 us; speedup vs baseline: 1.2506x; 1.2506x over previous
//
#include <hip/hip_runtime.h>
#include <math.h>

#define Hd 256
#define Wd 256
#define Cd 128
#define BIGV 1.0e9f

typedef float f32x4 __attribute__((ext_vector_type(4)));

static __device__ __forceinline__ float softplus_f(float x) {
    return fmaxf(x, 0.0f) + log1pf(expf(-fabsf(x)));
}

// ---- DPP helpers (gfx9/CDNA DPP controls; old = FLT_MAX = min identity) ----
#define FMAXBITS 0x7F7FFFFF
template<int CTRL, int RM>
static __device__ __forceinline__ float dpp_mv(float x) {
    return __int_as_float(__builtin_amdgcn_update_dpp(
        FMAXBITS, __float_as_int(x), CTRL, RM, 0xF, false));
}
template<int CTRL, int RM>
static __device__ __forceinline__ float dpp_min(float x) {
    return fminf(x, dpp_mv<CTRL, RM>(x));
}
// inclusive prefix-min across 64 lanes
static __device__ __forceinline__ float wave_prefmin(float x) {
    x = dpp_min<0x111, 0xF>(x);   // row_shr:1
    x = dpp_min<0x112, 0xF>(x);   // row_shr:2
    x = dpp_min<0x114, 0xF>(x);   // row_shr:4
    x = dpp_min<0x118, 0xF>(x);   // row_shr:8
    x = dpp_min<0x142, 0xA>(x);   // row_bcast15 -> rows 1,3
    x = dpp_min<0x143, 0xC>(x);   // row_bcast31 -> rows 2,3
    return x;
}

#define TILE 16
#define HPX 18
#define PXN 324
#define SP  325
#define CHUNK 32

// ---------------------------------------------------------------------------
// Kernel 1: COST-ONLY per-pixel work (proven R12 version, unchanged).
// ---------------------------------------------------------------------------
__global__ __launch_bounds__(256) void k_cost(
    const float* __restrict__ feat,
    float* __restrict__ out, float* __restrict__ costP)
{
    __shared__ float stage[CHUNK * SP];
    __shared__ float normL[PXN];

    const int t  = threadIdx.x;
    const int r0 = blockIdx.y * TILE;
    const int c0 = blockIdx.x * TILE;

    const int lr = t >> 4, lc = t & 15;
    const int r = r0 + lr, c = c0 + lc;
    const int px0 = (lr + 1) * HPX + (lc + 1);

    float dotv[8];
#pragma unroll
    for (int j = 0; j < 8; ++j) dotv[j] = 0.0f;

    for (int ch0 = 0; ch0 < Cd; ch0 += CHUNK) {
        __syncthreads();
        for (int i = t; i < PXN * 8; i += 256) {
            int px = i >> 3, f4 = i & 7;
            int pr = px / HPX;
            int pc = px - pr * HPX;
            int gr = r0 - 1 + pr, gc = c0 - 1 + pc;
            float4 v = make_float4(0.f, 0.f, 0.f, 0.f);
            if ((unsigned)gr < Hd && (unsigned)gc < Wd) {
                v = *reinterpret_cast<const float4*>(
                        &feat[(((gr << 8) + gc) * Cd) + ch0 + (f4 << 2)]);
            }
            int chb = f4 << 2;
            stage[(chb + 0) * SP + px] = v.x;
            stage[(chb + 1) * SP + px] = v.y;
            stage[(chb + 2) * SP + px] = v.z;
            stage[(chb + 3) * SP + px] = v.w;
        }
        __syncthreads();
        for (int px = t; px < PXN; px += 256) {
            float s = 0.0f;
#pragma unroll
            for (int ch = 0; ch < CHUNK; ++ch) {
                float v = stage[ch * SP + px];
                s = fmaf(v, v, s);
            }
            if (ch0 == 0) normL[px] = s; else normL[px] += s;
        }
        for (int ch = 0; ch < CHUNK; ++ch) {
            const float* pl = stage + ch * SP + px0;
            float x  = pl[0];
            float n0 = pl[-HPX - 1], n1 = pl[-HPX], n2 = pl[-HPX + 1];
            float n3 = pl[-1],                      n4 = pl[1];
            float n5 = pl[HPX - 1],  n6 = pl[HPX],  n7 = pl[HPX + 1];

            dotv[0] = fmaf(x, n0, dotv[0]);
            dotv[1] = fmaf(x, n1, dotv[1]);
            dotv[2] = fmaf(x, n2, dotv[2]);
            dotv[3] = fmaf(x, n3, dotv[3]);
            dotv[4] = fmaf(x, n4, dotv[4]);
            dotv[5] = fmaf(x, n5, dotv[5]);
            dotv[6] = fmaf(x, n6, dotv[6]);
            dotv[7] = fmaf(x, n7, dotv[7]);
        }
    }
    __syncthreads();

    const int p = (r << 8) + c;
    float np = fmaxf(sqrtf(normL[px0]), 1e-12f);
    const int drr[8] = {-1,-1,-1, 0, 0, 1, 1, 1};
    const int dcc[8] = {-1, 0, 1,-1, 1,-1, 0, 1};
    const int nof[8] = {-HPX-1,-HPX,-HPX+1,-1,1,HPX-1,HPX,HPX+1};
#pragma unroll
    for (int j = 0; j < 8; ++j) {
        int nr = r + drr[j], nc = c + dcc[j];
        float cj;
        if ((unsigned)nr < Hd && (unsigned)nc < Wd) {
            float nn = fmaxf(sqrtf(normL[px0 + nof[j]]), 1e-12f);
            cj = 1.0f - dotv[j] / (np * nn);
        } else {
            cj = BIGV;
        }
        costP[(j << 16) + p] = cj;
        out[p * 10 + 1 + j]  = cj;
    }
}

// ---------------------------------------------------------------------------
// Kernel 2: per-row exclusive prefix sums of horizontal edge costs (unchanged).
// ---------------------------------------------------------------------------
__global__ __launch_bounds__(64) void k_scan(
    const float* __restrict__ costP, float* __restrict__ PR, float* __restrict__ PRm)
{
    const int r = blockIdx.x;
    const int l = threadIdx.x;
    const int base = (r << 8) + (l << 2);

    {
        const float4 c4 = *(const float4*)&costP[(4 << 16) + base];
        float a0 = c4.x, a1 = a0 + c4.y, a2 = a1 + c4.z, a3 = a2 + c4.w;
        float ta = a3;
#pragma unroll
        for (int o = 1; o < 64; o <<= 1) {
            float xa = __shfl_up(ta, o, 64);
            if (l >= o) ta += xa;
        }
        float ea = __shfl_up(ta, 1, 64); if (l == 0) ea = 0.0f;
        float4 P; P.x = ea; P.y = ea + a0; P.z = ea + a1; P.w = ea + a2;
        *(float4*)&PR[base] = P;
    }
    {
        const float4 m = *(const float4*)&costP[(3 << 16) + (r << 8) + (252 - (l << 2))];
        float w0 = m.w, w1_ = m.z, w2_ = m.y, w3 = m.x;
        float a0 = w0, a1 = a0 + w1_, a2 = a1 + w2_, a3 = a2 + w3;
        float ta = a3;
#pragma unroll
        for (int o = 1; o < 64; o <<= 1) {
            float xa = __shfl_up(ta, o, 64);
            if (l >= o) ta += xa;
        }
        float ea = __shfl_up(ta, 1, 64); if (l == 0) ea = 0.0f;
        float4 P; P.x = ea; P.y = ea + a0; P.z = ea + a1; P.w = ea + a2;
        *(float4*)&PRm[base] = P;
    }
}

// ---------------------------------------------------------------------------
// R16 sweep core: single-chain (R1-proven math), but ALL sweep VMEM as
// volatile inline asm with hand-counted vmcnt. The compiler cannot sink
// volatile asm and must materialize "=v" outputs -> the 4-deep prefetch
// pipeline (issued 4 rows = ~600 cyc ahead) finally exists in hardware.
// FIFO accounting (all VMEM is asm, exact order): per row = 1 store + 4
// loads; group for row i is issued at row i-4. Waits: rows 0..2 use
// vmcnt(12/13/14), steady state vmcnt(15). Mirroring (M=1) is compile-time
// component renaming; source address pre-mirrored per lane.
// ---------------------------------------------------------------------------
template<int VD> static __device__ __forceinline__ int row_of(int ii) {
    int c = ii > 255 ? 255 : ii;
    return VD ? c : 255 - c;
}
template<int VD> static __device__ __forceinline__ int rowp_of(int ii) {
    int c = ii - 1; c = c < 0 ? 0 : (c > 255 ? 255 : c);
    return VD ? c : 255 - c;
}

template<int M, int VD>
static __device__ __forceinline__ void sweep_run(
    int l, int sr, int sc,
    const float* __restrict__ PRu,
    const float* __restrict__ cInP,
    const float* __restrict__ cStP,
    const float* __restrict__ cDeP,
    float* __restrict__ O)
{
    const int lane4 = l << 2;
    f32x4 sv = {BIGV, BIGV, BIGV, BIGV};
    {
        int kk = sc - lane4;
        if (kk == 0) sv[0] = 0.0f;
        if (kk == 1) sv[1] = 0.0f;
        if (kk == 2) sv[2] = 0.0f;
        if (kk == 3) sv[3] = 0.0f;
    }
    const int iStart = VD ? sr : 255 - sr;

    f32x4 bPR[4], bI[4], bS[4], bD[4];
    f32x4 Dp = {BIGV, BIGV, BIGV, BIGV};

    // mirrored component renaming (compile-time; matches old ld4m reversal)
#define KXc(v) (M ? (v)[3] : (v)[0])
#define KYc(v) (M ? (v)[2] : (v)[1])
#define KZc(v) (M ? (v)[1] : (v)[2])
#define KWc(v) (M ? (v)[0] : (v)[3])

#define SW_ISSUE(slot, jn) do {                                               \
        int rP_ = row_of<VD>(jn), rC_ = rowp_of<VD>(jn);                      \
        int voffP_ = ((rP_ << 8) + lane4) << 2;                               \
        int voffC_ = (M ? ((rC_ << 8) + 252 - lane4)                          \
                        : ((rC_ << 8) + lane4)) << 2;                         \
        asm volatile("global_load_dwordx4 %0, %1, %2"                         \
                     : "=v"(bPR[slot]) : "v"(voffP_), "s"(PRu));              \
        asm volatile("global_load_dwordx4 %0, %1, %2"                         \
                     : "=v"(bI[slot])  : "v"(voffC_), "s"(cInP));             \
        asm volatile("global_load_dwordx4 %0, %1, %2"                         \
                     : "=v"(bS[slot])  : "v"(voffC_), "s"(cStP));             \
        asm volatile("global_load_dwordx4 %0, %1, %2"                         \
                     : "=v"(bD[slot])  : "v"(voffC_), "s"(cDeP));             \
    } while (0)

#define SW_WAIT(n) do {                                                       \
        asm volatile("s_waitcnt vmcnt(" #n ")");                              \
        __builtin_amdgcn_sched_barrier(0);                                    \
    } while (0)

#define SW_BODY(slot, ivar) do {                                              \
        const int i__ = (ivar);                                               \
        const int r__ = VD ? i__ : 255 - i__;                                 \
        f32x4 PRc = bPR[slot];                                                \
        float tS0 = Dp[0] + KXc(bS[slot]), tS1 = Dp[1] + KYc(bS[slot]);       \
        float tS2 = Dp[2] + KZc(bS[slot]), tS3 = Dp[3] + KWc(bS[slot]);       \
        float tI0 = Dp[0] + KXc(bI[slot]), tI1 = Dp[1] + KYc(bI[slot]);       \
        float tI2 = Dp[2] + KZc(bI[slot]), tI3 = Dp[3] + KWc(bI[slot]);       \
        float tD0 = Dp[0] + KXc(bD[slot]), tD1 = Dp[1] + KYc(bD[slot]);       \
        float tD2 = Dp[2] + KZc(bD[slot]), tD3 = Dp[3] + KWc(bD[slot]);       \
        float tIm = dpp_mv<0x138, 0xF>(tI3);   /* wave_shr1 */                \
        float tDn = dpp_mv<0x130, 0xF>(tD0);   /* wave_shl1 */                \
        f32x4 cand;                                                           \
        cand[0] = fminf(tS0, fminf(tIm, tD1));                                \
        cand[1] = fminf(tS1, fminf(tI0, tD2));                                \
        cand[2] = fminf(tS2, fminf(tI1, tD3));                                \
        cand[3] = fminf(tS3, fminf(tI2, tDn));                                \
        if (i__ == iStart) {                                                  \
            cand[0] = fminf(cand[0], sv[0]); cand[1] = fminf(cand[1], sv[1]); \
            cand[2] = fminf(cand[2], sv[2]); cand[3] = fminf(cand[3], sv[3]); \
        }                                                                     \
        float z0 = cand[0] - PRc[0];                                          \
        float z1 = fminf(cand[1] - PRc[1], z0);                               \
        float z2 = fminf(cand[2] - PRc[2], z1);                               \
        float z3 = fminf(cand[3] - PRc[3], z2);                               \
        float w__ = wave_prefmin(z3);                                         \
        float e__ = dpp_mv<0x138, 0xF>(w__);   /* exclusive prefix */         \
        f32x4 D__;                                                            \
        D__[0] = PRc[0] + fminf(z0, e__);                                     \
        D__[1] = PRc[1] + fminf(z1, e__);                                     \
        D__[2] = PRc[2] + fminf(z2, e__);                                     \
        D__[3] = PRc[3] + fminf(z3, e__);                                     \
        int voffO_ = ((r__ << 8) + lane4) << 2;                               \
        asm volatile("global_store_dwordx4 %0, %1, %2"                        \
                     :: "v"(voffO_), "v"(D__), "s"(O));                       \
        Dp = D__;                                                             \
        SW_ISSUE(slot, i__ + 4);                                              \
    } while (0)

    // prologue: issue groups for rows 0..3 (16 loads in flight)
#pragma unroll
    for (int k = 0; k < 4; ++k) SW_ISSUE(k, k);

    // peeled rows 0..3 (exact FIFO counts), then steady state vmcnt(15)
    SW_WAIT(12); SW_BODY(0, 0);
    SW_WAIT(13); SW_BODY(1, 1);
    SW_WAIT(14); SW_BODY(2, 2);
    SW_WAIT(15); SW_BODY(3, 3);
    for (int ib = 4; ib < 256; ib += 4) {
        SW_WAIT(15); SW_BODY(0, ib + 0);
        SW_WAIT(15); SW_BODY(1, ib + 1);
        SW_WAIT(15); SW_BODY(2, ib + 2);
        SW_WAIT(15); SW_BODY(3, ib + 3);
    }
    asm volatile("s_waitcnt vmcnt(0)");   // drain stores before endpgm

#undef SW_ISSUE
#undef SW_WAIT
#undef SW_BODY
#undef KXc
#undef KYc
#undef KZc
#undef KWc
}

// ---------------------------------------------------------------------------
// Kernel 3 (R16): blocks 0..3 = asm-pipelined single-chain sweeps (R1's
// proven 4-block structure); blocks 4..259 = heuristic (unchanged, R1).
// ---------------------------------------------------------------------------
__global__ __launch_bounds__(256) void k_main(
    const float* __restrict__ feat,
    const float* __restrict__ w1, const float* __restrict__ b1,
    const float* __restrict__ w2, const float* __restrict__ b2,
    const float* __restrict__ dlt, const float* __restrict__ gmm,
    const float* __restrict__ bta, const int* __restrict__ endn,
    const float* __restrict__ costP, const float* __restrict__ PR,
    const float* __restrict__ PRm, const int* __restrict__ startn,
    float* __restrict__ out, float* __restrict__ distQ)
{
    if (blockIdx.x < 4) {
        const int l = threadIdx.x;
        if (l >= 64) return;
        __builtin_amdgcn_s_setprio(1);     // latency-critical chain wins issue
        const int sw  = blockIdx.x;
        const int sr  = startn[0];
        const int sc0 = startn[1];
        float* O = distQ + (sw << 16);
        // planes: vdown? inc/str/dec = (M?5:7)/6/(M?7:5) : (M?0:2)/1/(M?2:0)
        if (sw == 0)
            sweep_run<0,1>(l, sr, sc0,       PR,  costP + (7<<16), costP + (6<<16), costP + (5<<16), O);
        else if (sw == 1)
            sweep_run<1,1>(l, sr, 255 - sc0, PRm, costP + (5<<16), costP + (6<<16), costP + (7<<16), O);
        else if (sw == 2)
            sweep_run<0,0>(l, sr, sc0,       PR,  costP + (2<<16), costP + (1<<16), costP + (0<<16), O);
        else
            sweep_run<1,0>(l, sr, 255 - sc0, PRm, costP + (0<<16), costP + (1<<16), costP + (2<<16), O);
        return;
    }

    // ================= HEURISTIC PATH (unchanged, R1-proven) ===============
    __shared__ float  stage[CHUNK * SP];
    __shared__ float4 w1L[Cd * 8];
    __shared__ float  endfL[64];
    __shared__ float  vendL[64];
    __shared__ float  vendS;

    const int t  = threadIdx.x;
    const int b  = blockIdx.x - 4;
    const int r0 = (b >> 4) * TILE;
    const int c0 = (b & 15) * TILE;

    for (int i = t; i < Cd * 8; i += 256) w1L[i] = ((const float4*)w1)[i];
    const int er = endn[0], ec = endn[1];
    if (t < 64) {
        endfL[t] = feat[(er * Wd + ec) * Cd + t];
        float s1 = 0.0f, s2 = 0.0f;
#pragma unroll
        for (int dr = -1; dr <= 1; ++dr)
#pragma unroll
            for (int dc = -1; dc <= 1; ++dc) {
                int gr = er + dr, gc = ec + dc;
                if ((unsigned)gr < Hd && (unsigned)gc < Wd) {
                    float x = feat[((gr << 8) + gc) * Cd + 64 + t];
                    s1 += x; s2 = fmaf(x, x, s2);
                }
            }
        float m = s1 * (1.0f / 9.0f);
        vendL[t] = s2 * (1.0f / 9.0f) - m * m;
    }

    const int lr = t >> 4, lc = t & 15;
    const int r = r0 + lr, c = c0 + lc;
    const int px0 = (lr + 1) * HPX + (lc + 1);

    float4 hv[8];
#pragma unroll
    for (int j = 0; j < 8; ++j) hv[j] = make_float4(0.f, 0.f, 0.f, 0.f);
    float gm_acc = 0.0f, var_acc = 0.0f, abs_acc = 0.0f;

    for (int ch0 = 0; ch0 < Cd; ch0 += CHUNK) {
        __syncthreads();
        for (int i = t; i < PXN * 8; i += 256) {
            int px = i >> 3, f4 = i & 7;
            int pr = px / HPX;
            int pc = px - pr * HPX;
            int gr = r0 - 1 + pr, gc = c0 - 1 + pc;
            float4 v = make_float4(0.f, 0.f, 0.f, 0.f);
            if ((unsigned)gr < Hd && (unsigned)gc < Wd) {
                v = *reinterpret_cast<const float4*>(
                        &feat[(((gr << 8) + gc) * Cd) + ch0 + (f4 << 2)]);
            }
            int chb = f4 << 2;
            stage[(chb + 0) * SP + px] = v.x;
            stage[(chb + 1) * SP + px] = v.y;
            stage[(chb + 2) * SP + px] = v.z;
            stage[(chb + 3) * SP + px] = v.w;
        }
        __syncthreads();
        const bool is_hf = (ch0 >= 64);
        for (int ch = 0; ch < CHUNK; ++ch) {
            const float* pl = stage + ch * SP + px0;
            float x  = pl[0];
            float n0 = pl[-HPX - 1], n1 = pl[-HPX], n2 = pl[-HPX + 1];
            float n3 = pl[-1],                      n4 = pl[1];
            float n5 = pl[HPX - 1],  n6 = pl[HPX],  n7 = pl[HPX + 1];

            float gx = (n2 + 2.f * n4 + n7) - (n0 + 2.f * n3 + n5);
            float gy = (n5 + 2.f * n6 + n7) - (n0 + 2.f * n1 + n2);
            gm_acc += sqrtf(gx * gx + gy * gy);

            if (is_hf) {
                float s1 = x + n0 + n1 + n2 + n3 + n4 + n5 + n6 + n7;
                float s2 = x*x + n0*n0 + n1*n1 + n2*n2 + n3*n3 + n4*n4
                         + n5*n5 + n6*n6 + n7*n7;
                float m = s1 * (1.0f / 9.0f);
                var_acc += s2 * (1.0f / 9.0f) - m * m;
            } else {
                float dlf = x - endfL[ch0 + ch];
                abs_acc = fmaf(dlf, dlf, abs_acc);
            }

            const float4* __restrict__ wr4 = &w1L[(ch0 + ch) << 3];
#pragma unroll
            for (int j4 = 0; j4 < 8; ++j4) {
                float4 wv = wr4[j4];
                hv[j4].x = fmaf(x, wv.x, hv[j4].x);
                hv[j4].y = fmaf(x, wv.y, hv[j4].y);
                hv[j4].z = fmaf(x, wv.z, hv[j4].z);
                hv[j4].w = fmaf(x, wv.w, hv[j4].w);
            }
        }
    }
    __syncthreads();

    if (t < 64) {
        float v = vendL[t];
#pragma unroll
        for (int o = 32; o > 0; o >>= 1) v += __shfl_down(v, o, 64);
        if (t == 0) vendS = v;
    }
    __syncthreads();
    const float vend = vendS;

    const int p = (r << 8) + c;
    float geo  = gm_acc * (1.0f / 128.0f);
    float absp = sqrtf(abs_acc);
    float o = b2[0];
#pragma unroll
    for (int j4 = 0; j4 < 8; ++j4) {
#pragma unroll
        for (int cc = 0; cc < 4; ++cc) {
            int j = (j4 << 2) + cc;
            float hj = fmaxf(((const float*)&hv[j4])[cc] + b1[j], 0.0f);
            o = fmaf(hj, w2[j], o);
        }
    }
    float omg = 1.0f / (1.0f + expf(-o));
    float dS = softplus_f(dlt[0]);
    float gS = softplus_f(gmm[0]);
    float bS = softplus_f(bta[0]);
    float heur = dS * geo + omg * gS * (vend - var_acc)
               + (1.0f - omg) * bS * absp;
    out[p * 10] = fmaxf(heur, 0.0f);
}

// ---------------------------------------------------------------------------
// Kernel 4: merge the 4 quadrant planes (un-mirroring planes 1,3) -> out ch 9
// ---------------------------------------------------------------------------
__global__ __launch_bounds__(256) void k_merge(
    const float* __restrict__ distQ, float* __restrict__ out)
{
    int p  = blockIdx.x * 256 + threadIdx.x;
    int pm = (p & ~255) + (255 - (p & 255));
    float v = fminf(fminf(distQ[p],           distQ[(2 << 16) + p]),
                    fminf(distQ[(1 << 16) + pm], distQ[(3 << 16) + pm]));
    out[p * 10 + 9] = fminf(v, BIGV);
}

// ---------------------------------------------------------------------------
extern "C" void kernel_launch(void* const* d_in, const int* in_sizes, int n_in,
                              void* d_out, int out_size, void* d_ws, size_t ws_size,
                              hipStream_t stream)
{
    const float* feat  = (const float*)d_in[0];
    const float* dlt   = (const float*)d_in[1];
    const float* gmm   = (const float*)d_in[2];
    const float* bta   = (const float*)d_in[3];
    const float* w1    = (const float*)d_in[4];
    const float* b1    = (const float*)d_in[5];
    const float* w2    = (const float*)d_in[6];
    const float* b2    = (const float*)d_in[7];
    const int*   startn= (const int*)d_in[8];
    const int*   endn  = (const int*)d_in[9];
    float* out = (float*)d_out;
    float* ws  = (float*)d_ws;

    float* costP = ws;                   // 8 planes
    float* PR    = ws + 8  * 65536;
    float* PRm   = ws + 9  * 65536;
    float* distQ = ws + 10 * 65536;      // 4 quadrant planes

    dim3 g16(16, 16);
    k_cost<<<g16, 256, 0, stream>>>(feat, out, costP);
    k_scan<<<256, 64, 0, stream>>>(costP, PR, PRm);
    k_main<<<260, 256, 0, stream>>>(feat, w1, b1, w2, b2, dlt, gmm, bta, endn,
                                    costP, PR, PRm, startn, out, distQ);
    k_merge<<<256, 256, 0, stream>>>(distQ, out);
}